// Round 1
// baseline (122.246 us; speedup 1.0000x reference)
//
#include <hip/hip_runtime.h>
#include <cstdint>

#pragma clang fp contract(off)

#define P_N 2048
#define F_N 8192
#define V_N 2048

#define TPB 256
#define FACES_PER_TILE 256
#define FLOATS_PER_FACE 24  // 21 used, padded to 24 for 16B alignment

// Compute barycentric weights of closest point on triangle + squared distance,
// replicating the reference's exact f32 expression tree (contract off).
__device__ __forceinline__ void tri_eval(
    float px, float py, float pz,
    float ax, float ay, float az,
    float bx, float by, float bz,
    float cx, float cy, float cz,
    float abx, float aby, float abz,
    float acx, float acy, float acz,
    float daab, float daac, float dbab, float dbac, float dcab, float dcac,
    float& w1o, float& w2o, float& w3o, float& disto)
{
#pragma clang fp contract(off)
    // pab = p . ab  (fma chain, matching Eigen/XLA gemm accumulation)
    float pab = fmaf(pz, abz, fmaf(py, aby, px * abx));
    float pac = fmaf(pz, acz, fmaf(py, acy, px * acx));

    float d1 = pab - daab;
    float d2 = pac - daac;
    float d3 = pab - dbab;
    float d4 = pac - dbac;
    float d5 = pab - dcab;
    float d6 = pac - dcac;

    float vc = d1 * d4 - d3 * d2;
    float vb = d5 * d2 - d1 * d6;
    float va = d3 * d6 - d5 * d4;

    float denom = (va + vb) + vc;
    float dn = (denom == 0.0f) ? 1.0f : denom;
    float v7 = vb / dn;
    float w7 = vc / dn;
    float w1 = (1.0f - v7) - w7;
    float w2 = v7;
    float w3 = w7;

    // region 6 (edge bc)
    float e63 = d4 - d3;
    float e65 = d5 - d6;
    float t6d = e63 + e65; t6d = (t6d == 0.0f) ? 1.0f : t6d;
    float t6 = e63 / t6d;
    if ((va <= 0.0f) & (e63 >= 0.0f) & (e65 >= 0.0f)) { w1 = 0.0f; w2 = 1.0f - t6; w3 = t6; }

    // region 5 (edge ac)
    float t5d = d2 - d6; t5d = (t5d == 0.0f) ? 1.0f : t5d;
    float t5 = d2 / t5d;
    if ((vb <= 0.0f) & (d2 >= 0.0f) & (d6 <= 0.0f)) { w1 = 1.0f - t5; w2 = 0.0f; w3 = t5; }

    // region 4 (vertex c)
    if ((d6 >= 0.0f) & (d5 <= d6)) { w1 = 0.0f; w2 = 0.0f; w3 = 1.0f; }

    // region 3 (edge ab)
    float t3d = d1 - d3; t3d = (t3d == 0.0f) ? 1.0f : t3d;
    float t3 = d1 / t3d;
    if ((vc <= 0.0f) & (d1 >= 0.0f) & (d3 <= 0.0f)) { w1 = 1.0f - t3; w2 = t3; w3 = 0.0f; }

    // region 2 (vertex b)
    if ((d3 >= 0.0f) & (d4 <= d3)) { w1 = 0.0f; w2 = 1.0f; w3 = 0.0f; }

    // region 1 (vertex a)
    if ((d1 <= 0.0f) & (d2 <= 0.0f)) { w1 = 1.0f; w2 = 0.0f; w3 = 0.0f; }

    // cp = w1*a + w2*b + w3*c ; dist = |p - cp|^2, same association order
    float cpx = (w1 * ax + w2 * bx) + w3 * cx;
    float cpy = (w1 * ay + w2 * by) + w3 * cy;
    float cpz = (w1 * az + w2 * bz) + w3 * cz;
    float dx = px - cpx, dy = py - cpy, dz = pz - cpz;
    float dist = (dx * dx + dy * dy) + dz * dz;

    w1o = w1; w2o = w2; w3o = w3; disto = dist;
}

// Build the 21 per-face constants, matching reference rounding:
// ab = b - a, ac = c - a, dots = sum(x*y) with ((m0+m1)+m2) association.
__device__ __forceinline__ void face_setup(
    const float* __restrict__ vertices, const int* __restrict__ faces, int f,
    float* fd)
{
#pragma clang fp contract(off)
    int i0 = faces[3 * f + 0];
    int i1 = faces[3 * f + 1];
    int i2 = faces[3 * f + 2];
    float ax = vertices[3 * i0 + 0], ay = vertices[3 * i0 + 1], az = vertices[3 * i0 + 2];
    float bx = vertices[3 * i1 + 0], by = vertices[3 * i1 + 1], bz = vertices[3 * i1 + 2];
    float cx = vertices[3 * i2 + 0], cy = vertices[3 * i2 + 1], cz = vertices[3 * i2 + 2];
    float abx = bx - ax, aby = by - ay, abz = bz - az;
    float acx = cx - ax, acy = cy - ay, acz = cz - az;
    float daab = (ax * abx + ay * aby) + az * abz;
    float daac = (ax * acx + ay * acy) + az * acz;
    float dbab = (bx * abx + by * aby) + bz * abz;
    float dbac = (bx * acx + by * acy) + bz * acz;
    float dcab = (cx * abx + cy * aby) + cz * abz;
    float dcac = (cx * acx + cy * acy) + cz * acz;
    fd[0] = ax;  fd[1] = ay;  fd[2] = az;
    fd[3] = bx;  fd[4] = by;  fd[5] = bz;
    fd[6] = cx;  fd[7] = cy;  fd[8] = cz;
    fd[9] = abx; fd[10] = aby; fd[11] = abz;
    fd[12] = acx; fd[13] = acy; fd[14] = acz;
    fd[15] = daab; fd[16] = daac; fd[17] = dbab;
    fd[18] = dbac; fd[19] = dcab; fd[20] = dcac;
}

__global__ __launch_bounds__(TPB) void k_scan(
    const float* __restrict__ points,
    const float* __restrict__ vertices,
    const int* __restrict__ faces,
    unsigned long long* __restrict__ best)
{
    __shared__ float sf[FACES_PER_TILE][FLOATS_PER_FACE];

    const int pblk = blockIdx.x;  // 0..P_N/TPB-1
    const int fblk = blockIdx.y;  // 0..F_N/FACES_PER_TILE-1
    const int t = threadIdx.x;

    // stage this block's face chunk into LDS
    {
        int f = fblk * FACES_PER_TILE + t;
        float fd[21];
        face_setup(vertices, faces, f, fd);
#pragma unroll
        for (int k = 0; k < 21; ++k) sf[t][k] = fd[k];
    }
    __syncthreads();

    const int p = pblk * TPB + t;
    const float px = points[3 * p + 0];
    const float py = points[3 * p + 1];
    const float pz = points[3 * p + 2];

    unsigned long long bk = ~0ull;
    const int fbase = fblk * FACES_PER_TILE;
#pragma unroll 4
    for (int j = 0; j < FACES_PER_TILE; ++j) {
        const float* fd = &sf[j][0];
        float w1, w2, w3, dist;
        tri_eval(px, py, pz,
                 fd[0], fd[1], fd[2], fd[3], fd[4], fd[5], fd[6], fd[7], fd[8],
                 fd[9], fd[10], fd[11], fd[12], fd[13], fd[14],
                 fd[15], fd[16], fd[17], fd[18], fd[19], fd[20],
                 w1, w2, w3, dist);
        unsigned int db = __float_as_uint(dist);
        if (dist != dist) db = 0u;  // NaN acts as -inf (numpy argmin returns first NaN)
        unsigned long long key = ((unsigned long long)db << 32) | (unsigned int)(fbase + j);
        bk = (key < bk) ? key : bk;
    }
    atomicMin(&best[p], bk);
}

__global__ __launch_bounds__(TPB) void k_final(
    const float* __restrict__ points,
    const float* __restrict__ vertices,
    const int* __restrict__ faces,
    const unsigned long long* __restrict__ best,
    float* __restrict__ out)
{
    const int p = blockIdx.x * TPB + threadIdx.x;
    if (p >= P_N) return;
    unsigned long long bk = best[p];
    int f = (int)(bk & 0xffffffffull);

    float fd[21];
    face_setup(vertices, faces, f, fd);

    const float px = points[3 * p + 0];
    const float py = points[3 * p + 1];
    const float pz = points[3 * p + 2];
    float w1, w2, w3, dist;
    tri_eval(px, py, pz,
             fd[0], fd[1], fd[2], fd[3], fd[4], fd[5], fd[6], fd[7], fd[8],
             fd[9], fd[10], fd[11], fd[12], fd[13], fd[14],
             fd[15], fd[16], fd[17], fd[18], fd[19], fd[20],
             w1, w2, w3, dist);

    out[p] = (float)f;
    out[P_N + p] = w1;
    out[2 * P_N + p] = w2;
    out[3 * P_N + p] = w3;
}

extern "C" void kernel_launch(void* const* d_in, const int* in_sizes, int n_in,
                              void* d_out, int out_size, void* d_ws, size_t ws_size,
                              hipStream_t stream)
{
    const float* points = (const float*)d_in[0];
    const float* vertices = (const float*)d_in[1];
    const int* faces = (const int*)d_in[2];
    float* out = (float*)d_out;
    unsigned long long* best = (unsigned long long*)d_ws;

    // init packed (dist,idx) keys to max
    hipMemsetAsync(d_ws, 0xFF, P_N * sizeof(unsigned long long), stream);

    dim3 grid(P_N / TPB, F_N / FACES_PER_TILE);
    k_scan<<<grid, TPB, 0, stream>>>(points, vertices, faces, best);
    k_final<<<(P_N + TPB - 1) / TPB, TPB, 0, stream>>>(points, vertices, faces, best, out);
}

// Round 3
// 68.933 us; speedup vs baseline: 1.7734x; 1.7734x over previous
//
#include <hip/hip_runtime.h>
#include <cstdint>

#pragma clang fp contract(off)

#define P_N 2048
#define F_N 8192
#define V_N 2048

#define TPB 256
#define FACES_PER_TILE 32
#define FLOATS_PER_FACE 24  // 21 used, padded

// Build the 21 per-face constants, matching reference rounding:
// ab = b - a, ac = c - a, dots = sum(x*y) with ((m0+m1)+m2) association.
// These are per-face in the reference too (jnp.sum(a*ab,-1)), so exact.
__device__ __forceinline__ void face_setup(
    const float* __restrict__ vertices, const int* __restrict__ faces, int f,
    float* fd)
{
#pragma clang fp contract(off)
    int i0 = faces[3 * f + 0];
    int i1 = faces[3 * f + 1];
    int i2 = faces[3 * f + 2];
    float ax = vertices[3 * i0 + 0], ay = vertices[3 * i0 + 1], az = vertices[3 * i0 + 2];
    float bx = vertices[3 * i1 + 0], by = vertices[3 * i1 + 1], bz = vertices[3 * i1 + 2];
    float cx = vertices[3 * i2 + 0], cy = vertices[3 * i2 + 1], cz = vertices[3 * i2 + 2];
    float abx = bx - ax, aby = by - ay, abz = bz - az;
    float acx = cx - ax, acy = cy - ay, acz = cz - az;
    float daab = (ax * abx + ay * aby) + az * abz;
    float daac = (ax * acx + ay * acy) + az * acz;
    float dbab = (bx * abx + by * aby) + bz * abz;
    float dbac = (bx * acx + by * acy) + bz * acz;
    float dcab = (cx * abx + cy * aby) + cz * abz;
    float dcac = (cx * acx + cy * acy) + cz * acz;
    fd[0] = ax;  fd[1] = ay;  fd[2] = az;
    fd[3] = bx;  fd[4] = by;  fd[5] = bz;
    fd[6] = cx;  fd[7] = cy;  fd[8] = cz;
    fd[9] = abx; fd[10] = aby; fd[11] = abz;
    fd[12] = acx; fd[13] = acy; fd[14] = acz;
    fd[15] = daab; fd[16] = daac; fd[17] = dbab;
    fd[18] = dbac; fd[19] = dcab; fd[20] = dcac;
}

// Exact (bit-identical to reference) closest-point weights + squared distance.
__device__ __forceinline__ void tri_eval_exact(
    float px, float py, float pz,
    const float* fd,
    float& w1o, float& w2o, float& w3o, float& disto)
{
#pragma clang fp contract(off)
    const float ax = fd[0], ay = fd[1], az = fd[2];
    const float bx = fd[3], by = fd[4], bz = fd[5];
    const float cx = fd[6], cy = fd[7], cz = fd[8];
    const float abx = fd[9], aby = fd[10], abz = fd[11];
    const float acx = fd[12], acy = fd[13], acz = fd[14];
    const float daab = fd[15], daac = fd[16], dbab = fd[17];
    const float dbac = fd[18], dcab = fd[19], dcac = fd[20];

    float pab = fmaf(pz, abz, fmaf(py, aby, px * abx));
    float pac = fmaf(pz, acz, fmaf(py, acy, px * acx));

    float d1 = pab - daab;
    float d2 = pac - daac;
    float d3 = pab - dbab;
    float d4 = pac - dbac;
    float d5 = pab - dcab;
    float d6 = pac - dcac;

    float vc = d1 * d4 - d3 * d2;
    float vb = d5 * d2 - d1 * d6;
    float va = d3 * d6 - d5 * d4;

    float denom = (va + vb) + vc;
    float dn = (denom == 0.0f) ? 1.0f : denom;
    float v7 = vb / dn;
    float w7 = vc / dn;
    float w1 = (1.0f - v7) - w7;
    float w2 = v7;
    float w3 = w7;

    float e63 = d4 - d3;
    float e65 = d5 - d6;
    float t6d = e63 + e65; t6d = (t6d == 0.0f) ? 1.0f : t6d;
    float t6 = e63 / t6d;
    if ((va <= 0.0f) & (e63 >= 0.0f) & (e65 >= 0.0f)) { w1 = 0.0f; w2 = 1.0f - t6; w3 = t6; }

    float t5d = d2 - d6; t5d = (t5d == 0.0f) ? 1.0f : t5d;
    float t5 = d2 / t5d;
    if ((vb <= 0.0f) & (d2 >= 0.0f) & (d6 <= 0.0f)) { w1 = 1.0f - t5; w2 = 0.0f; w3 = t5; }

    if ((d6 >= 0.0f) & (d5 <= d6)) { w1 = 0.0f; w2 = 0.0f; w3 = 1.0f; }

    float t3d = d1 - d3; t3d = (t3d == 0.0f) ? 1.0f : t3d;
    float t3 = d1 / t3d;
    if ((vc <= 0.0f) & (d1 >= 0.0f) & (d3 <= 0.0f)) { w1 = 1.0f - t3; w2 = t3; w3 = 0.0f; }

    if ((d3 >= 0.0f) & (d4 <= d3)) { w1 = 0.0f; w2 = 1.0f; w3 = 0.0f; }

    if ((d1 <= 0.0f) & (d2 <= 0.0f)) { w1 = 1.0f; w2 = 0.0f; w3 = 0.0f; }

    float cpx = (w1 * ax + w2 * bx) + w3 * cx;
    float cpy = (w1 * ay + w2 * by) + w3 * cy;
    float cpz = (w1 * az + w2 * bz) + w3 * cz;
    float dx = px - cpx, dy = py - cpy, dz = pz - cpz;
    float dist = (dx * dx + dy * dy) + dz * dz;

    w1o = w1; w2o = w2; w3o = w3; disto = dist;
}

__global__ __launch_bounds__(TPB) void k_scan(
    const float* __restrict__ points,
    const float* __restrict__ vertices,
    const int* __restrict__ faces,
    unsigned long long* __restrict__ best)
{
    __shared__ float sf[FACES_PER_TILE][FLOATS_PER_FACE];

    const int pblk = blockIdx.x;  // 0..P_N/TPB-1
    const int fblk = blockIdx.y;  // 0..F_N/FACES_PER_TILE-1
    const int t = threadIdx.x;

    if (t < FACES_PER_TILE) {
        int f = fblk * FACES_PER_TILE + t;
        float fd[21];
        face_setup(vertices, faces, f, fd);
#pragma unroll
        for (int k = 0; k < 21; ++k) sf[t][k] = fd[k];
    }
    __syncthreads();

    const int p = pblk * TPB + t;
    const float px = points[3 * p + 0];
    const float py = points[3 * p + 1];
    const float pz = points[3 * p + 2];

    // running min on dist bits (dist >= 0 so uint order == float order);
    // strict less keeps the FIRST minimum (lowest face idx), matching numpy.
    unsigned int bestdb = 0xffffffffu;
    int bestf = 0;
    const int fbase = fblk * FACES_PER_TILE;

#pragma unroll 4
    for (int j = 0; j < FACES_PER_TILE; ++j) {
        float w1, w2, w3, dist;
        tri_eval_exact(px, py, pz, &sf[j][0], w1, w2, w3, dist);
        unsigned int db = __float_as_uint(dist);
        if (dist != dist) db = 0u;  // NaN acts as -inf (numpy argmin: first NaN wins)
        if (db < bestdb) { bestdb = db; bestf = fbase + j; }
    }

    unsigned long long key =
        ((unsigned long long)bestdb << 32) | (unsigned int)bestf;
    atomicMin(&best[p], key);
}

__global__ __launch_bounds__(TPB) void k_final(
    const float* __restrict__ points,
    const float* __restrict__ vertices,
    const int* __restrict__ faces,
    const unsigned long long* __restrict__ best,
    float* __restrict__ out)
{
    const int p = blockIdx.x * TPB + threadIdx.x;
    if (p >= P_N) return;
    unsigned long long bk = best[p];
    int f = (int)(bk & 0xffffffffull);

    float fd[21];
    face_setup(vertices, faces, f, fd);

    const float px = points[3 * p + 0];
    const float py = points[3 * p + 1];
    const float pz = points[3 * p + 2];
    float w1, w2, w3, dist;
    tri_eval_exact(px, py, pz, fd, w1, w2, w3, dist);

    out[p] = (float)f;
    out[P_N + p] = w1;
    out[2 * P_N + p] = w2;
    out[3 * P_N + p] = w3;
}

extern "C" void kernel_launch(void* const* d_in, const int* in_sizes, int n_in,
                              void* d_out, int out_size, void* d_ws, size_t ws_size,
                              hipStream_t stream)
{
    const float* points = (const float*)d_in[0];
    const float* vertices = (const float*)d_in[1];
    const int* faces = (const int*)d_in[2];
    float* out = (float*)d_out;
    unsigned long long* best = (unsigned long long*)d_ws;

    hipMemsetAsync(d_ws, 0xFF, P_N * sizeof(unsigned long long), stream);

    dim3 grid(P_N / TPB, F_N / FACES_PER_TILE);
    k_scan<<<grid, TPB, 0, stream>>>(points, vertices, faces, best);
    k_final<<<(P_N + TPB - 1) / TPB, TPB, 0, stream>>>(points, vertices, faces, best, out);
}

// Round 4
// 60.231 us; speedup vs baseline: 2.0296x; 1.1445x over previous
//
#include <hip/hip_runtime.h>
#include <cstdint>

#pragma clang fp contract(off)

#define P_N 2048
#define F_N 8192
#define V_N 2048

#define TPB 256
#define FACES_PER_TILE 32
#define FLOATS_PER_FACE 24  // 21 used, padded to 6 x float4

// Build the 21 per-face constants, matching reference rounding:
// ab = b - a, ac = c - a, dots = sum(x*y) with ((m0+m1)+m2) association.
__device__ __forceinline__ void face_setup(
    const float* __restrict__ vertices, const int* __restrict__ faces, int f,
    float* fd)
{
#pragma clang fp contract(off)
    int i0 = faces[3 * f + 0];
    int i1 = faces[3 * f + 1];
    int i2 = faces[3 * f + 2];
    float ax = vertices[3 * i0 + 0], ay = vertices[3 * i0 + 1], az = vertices[3 * i0 + 2];
    float bx = vertices[3 * i1 + 0], by = vertices[3 * i1 + 1], bz = vertices[3 * i1 + 2];
    float cx = vertices[3 * i2 + 0], cy = vertices[3 * i2 + 1], cz = vertices[3 * i2 + 2];
    float abx = bx - ax, aby = by - ay, abz = bz - az;
    float acx = cx - ax, acy = cy - ay, acz = cz - az;
    float daab = (ax * abx + ay * aby) + az * abz;
    float daac = (ax * acx + ay * acy) + az * acz;
    float dbab = (bx * abx + by * aby) + bz * abz;
    float dbac = (bx * acx + by * acy) + bz * acz;
    float dcab = (cx * abx + cy * aby) + cz * abz;
    float dcac = (cx * acx + cy * acy) + cz * acz;
    fd[0] = ax;  fd[1] = ay;  fd[2] = az;
    fd[3] = bx;  fd[4] = by;  fd[5] = bz;
    fd[6] = cx;  fd[7] = cy;  fd[8] = cz;
    fd[9] = abx; fd[10] = aby; fd[11] = abz;
    fd[12] = acx; fd[13] = acy; fd[14] = acz;
    fd[15] = daab; fd[16] = daac; fd[17] = dbab;
    fd[18] = dbac; fd[19] = dcab; fd[20] = dcac;
}

// Exact (bit-identical to reference) eval — 5 divides. Used only in k_final.
__device__ __forceinline__ void tri_eval_exact(
    float px, float py, float pz,
    const float* fd,
    float& w1o, float& w2o, float& w3o, float& disto)
{
#pragma clang fp contract(off)
    const float ax = fd[0], ay = fd[1], az = fd[2];
    const float bx = fd[3], by = fd[4], bz = fd[5];
    const float cx = fd[6], cy = fd[7], cz = fd[8];
    const float abx = fd[9], aby = fd[10], abz = fd[11];
    const float acx = fd[12], acy = fd[13], acz = fd[14];
    const float daab = fd[15], daac = fd[16], dbab = fd[17];
    const float dbac = fd[18], dcab = fd[19], dcac = fd[20];

    float pab = fmaf(pz, abz, fmaf(py, aby, px * abx));
    float pac = fmaf(pz, acz, fmaf(py, acy, px * acx));

    float d1 = pab - daab;
    float d2 = pac - daac;
    float d3 = pab - dbab;
    float d4 = pac - dbac;
    float d5 = pab - dcab;
    float d6 = pac - dcac;

    float vc = d1 * d4 - d3 * d2;
    float vb = d5 * d2 - d1 * d6;
    float va = d3 * d6 - d5 * d4;

    float denom = (va + vb) + vc;
    float dn = (denom == 0.0f) ? 1.0f : denom;
    float v7 = vb / dn;
    float w7 = vc / dn;
    float w1 = (1.0f - v7) - w7;
    float w2 = v7;
    float w3 = w7;

    float e63 = d4 - d3;
    float e65 = d5 - d6;
    float t6d = e63 + e65; t6d = (t6d == 0.0f) ? 1.0f : t6d;
    float t6 = e63 / t6d;
    if ((va <= 0.0f) & (e63 >= 0.0f) & (e65 >= 0.0f)) { w1 = 0.0f; w2 = 1.0f - t6; w3 = t6; }

    float t5d = d2 - d6; t5d = (t5d == 0.0f) ? 1.0f : t5d;
    float t5 = d2 / t5d;
    if ((vb <= 0.0f) & (d2 >= 0.0f) & (d6 <= 0.0f)) { w1 = 1.0f - t5; w2 = 0.0f; w3 = t5; }

    if ((d6 >= 0.0f) & (d5 <= d6)) { w1 = 0.0f; w2 = 0.0f; w3 = 1.0f; }

    float t3d = d1 - d3; t3d = (t3d == 0.0f) ? 1.0f : t3d;
    float t3 = d1 / t3d;
    if ((vc <= 0.0f) & (d1 >= 0.0f) & (d3 <= 0.0f)) { w1 = 1.0f - t3; w2 = t3; w3 = 0.0f; }

    if ((d3 >= 0.0f) & (d4 <= d3)) { w1 = 0.0f; w2 = 1.0f; w3 = 0.0f; }

    if ((d1 <= 0.0f) & (d2 <= 0.0f)) { w1 = 1.0f; w2 = 0.0f; w3 = 0.0f; }

    float cpx = (w1 * ax + w2 * bx) + w3 * cx;
    float cpy = (w1 * ay + w2 * by) + w3 * cy;
    float cpz = (w1 * az + w2 * bz) + w3 * cz;
    float dx = px - cpx, dy = py - cpy, dz = pz - cpz;
    float dist = (dx * dx + dy * dy) + dz * dz;

    w1o = w1; w2o = w2; w3o = w3; disto = dist;
}

__global__ __launch_bounds__(TPB) void k_scan(
    const float* __restrict__ points,
    const float* __restrict__ vertices,
    const int* __restrict__ faces,
    unsigned long long* __restrict__ best)
{
    __shared__ float sf[FACES_PER_TILE][FLOATS_PER_FACE];

    const int pblk = blockIdx.x;  // 0..P_N/TPB-1
    const int fblk = blockIdx.y;  // 0..F_N/FACES_PER_TILE-1
    const int t = threadIdx.x;

    if (t < FACES_PER_TILE) {
        int f = fblk * FACES_PER_TILE + t;
        float fd[21];
        face_setup(vertices, faces, f, fd);
#pragma unroll
        for (int k = 0; k < 21; ++k) sf[t][k] = fd[k];
    }
    __syncthreads();

    const int p = pblk * TPB + t;
    const float px = points[3 * p + 0];
    const float py = points[3 * p + 1];
    const float pz = points[3 * p + 2];

    unsigned int bestdb = 0xffffffffu;
    int bestf = 0;
    const int fbase = fblk * FACES_PER_TILE;

#pragma unroll 4
    for (int j = 0; j < FACES_PER_TILE; ++j) {
        const float4* fv = (const float4*)&sf[j][0];
        float4 v0 = fv[0], v1 = fv[1], v2 = fv[2], v3 = fv[3], v4 = fv[4], v5 = fv[5];
        const float ax = v0.x, ay = v0.y, az = v0.z;
        const float bx = v0.w, by = v1.x, bz = v1.y;
        const float cx = v1.z, cy = v1.w, cz = v2.x;
        const float abx = v2.y, aby = v2.z, abz = v2.w;
        const float acx = v3.x, acy = v3.y, acz = v3.z;
        const float daab = v3.w, daac = v4.x, dbab = v4.y;
        const float dbac = v4.z, dcab = v4.w, dcac = v5.x;

        float pab = fmaf(pz, abz, fmaf(py, aby, px * abx));
        float pac = fmaf(pz, acz, fmaf(py, acy, px * acx));

        float d1 = pab - daab;
        float d2 = pac - daac;
        float d3 = pab - dbab;
        float d4 = pac - dbac;
        float d5 = pab - dcab;
        float d6 = pac - dcac;

        float vc = d1 * d4 - d3 * d2;
        float vb = d5 * d2 - d1 * d6;
        float va = d3 * d6 - d5 * d4;

        float e63 = d4 - d3;
        float e65 = d5 - d6;
        float denom = (va + vb) + vc;

        // region masks (reference priority: m1 > m2 > m3 > m4 > m5 > m6 > interior)
        bool m1 = (d1 <= 0.0f) & (d2 <= 0.0f);
        bool m2 = (d3 >= 0.0f) & (d4 <= d3);
        bool m3 = (vc <= 0.0f) & (d1 >= 0.0f) & (d3 <= 0.0f);
        bool m4 = (d6 >= 0.0f) & (d5 <= d6);
        bool m5 = (vb <= 0.0f) & (d2 >= 0.0f) & (d6 <= 0.0f);
        bool m6 = (va <= 0.0f) & (e63 >= 0.0f) & (e65 >= 0.0f);
        bool anym = m1 | m2 | m3 | m4 | m5 | m6;

        // select the one division the winning region needs (q2 only for interior)
        float n1  = m1 ? 0.0f : m2 ? 0.0f : m3 ? d1          : m4 ? 0.0f : m5 ? d2          : m6 ? e63         : vb;
        float ds1 = m1 ? 1.0f : m2 ? 1.0f : m3 ? (d1 - d3)   : m4 ? 1.0f : m5 ? (d2 - d6)   : m6 ? (e63 + e65) : denom;
        ds1 = (ds1 == 0.0f) ? 1.0f : ds1;
        float n2  = anym ? 0.0f : vc;
        float ds2 = anym ? 1.0f : ((denom == 0.0f) ? 1.0f : denom);

        float q1 = n1 / ds1;
        float q2 = n2 / ds2;
        float u = (1.0f - q1) - q2;  // == 1-q1 bit-exactly when q2==0

        float w1 = m1 ? 1.0f : m2 ? 0.0f : m3 ? u    : m4 ? 0.0f : m5 ? u    : m6 ? 0.0f : u;
        float w2 = m1 ? 0.0f : m2 ? 1.0f : m3 ? q1   : m4 ? 0.0f : m5 ? 0.0f : m6 ? u    : q1;
        float w3 = m1 ? 0.0f : m2 ? 0.0f : m3 ? 0.0f : m4 ? 1.0f : m5 ? q1   : m6 ? q1   : q2;

        float cpx = (w1 * ax + w2 * bx) + w3 * cx;
        float cpy = (w1 * ay + w2 * by) + w3 * cy;
        float cpz = (w1 * az + w2 * bz) + w3 * cz;
        float dx = px - cpx, dy = py - cpy, dz = pz - cpz;
        float dist = (dx * dx + dy * dy) + dz * dz;

        unsigned int db = __float_as_uint(dist);
        if (dist != dist) db = 0u;  // NaN acts as -inf (numpy argmin: first NaN wins)
        if (db < bestdb) { bestdb = db; bestf = fbase + j; }
    }

    unsigned long long key =
        ((unsigned long long)bestdb << 32) | (unsigned int)bestf;
    atomicMin(&best[p], key);
}

__global__ __launch_bounds__(TPB) void k_final(
    const float* __restrict__ points,
    const float* __restrict__ vertices,
    const int* __restrict__ faces,
    const unsigned long long* __restrict__ best,
    float* __restrict__ out)
{
    const int p = blockIdx.x * TPB + threadIdx.x;
    if (p >= P_N) return;
    unsigned long long bk = best[p];
    int f = (int)(bk & 0xffffffffull);

    float fd[21];
    face_setup(vertices, faces, f, fd);

    const float px = points[3 * p + 0];
    const float py = points[3 * p + 1];
    const float pz = points[3 * p + 2];
    float w1, w2, w3, dist;
    tri_eval_exact(px, py, pz, fd, w1, w2, w3, dist);

    out[p] = (float)f;
    out[P_N + p] = w1;
    out[2 * P_N + p] = w2;
    out[3 * P_N + p] = w3;
}

extern "C" void kernel_launch(void* const* d_in, const int* in_sizes, int n_in,
                              void* d_out, int out_size, void* d_ws, size_t ws_size,
                              hipStream_t stream)
{
    const float* points = (const float*)d_in[0];
    const float* vertices = (const float*)d_in[1];
    const int* faces = (const int*)d_in[2];
    float* out = (float*)d_out;
    unsigned long long* best = (unsigned long long*)d_ws;

    hipMemsetAsync(d_ws, 0xFF, P_N * sizeof(unsigned long long), stream);

    dim3 grid(P_N / TPB, F_N / FACES_PER_TILE);
    k_scan<<<grid, TPB, 0, stream>>>(points, vertices, faces, best);
    k_final<<<(P_N + TPB - 1) / TPB, TPB, 0, stream>>>(points, vertices, faces, best, out);
}

// Round 5
// 55.954 us; speedup vs baseline: 2.1848x; 1.0765x over previous
//
#include <hip/hip_runtime.h>
#include <cstdint>

#pragma clang fp contract(off)

typedef float v2f __attribute__((ext_vector_type(2)));

#define P_N 2048
#define F_N 8192
#define V_N 2048

#define TPB 256
#define FACES_PER_TILE 32

// Build the 21 per-face constants, matching reference rounding:
// ab = b - a, ac = c - a, dots = sum(x*y) with ((m0+m1)+m2) association.
__device__ __forceinline__ void face_setup(
    const float* __restrict__ vertices, const int* __restrict__ faces, int f,
    float* fd)
{
#pragma clang fp contract(off)
    int i0 = faces[3 * f + 0];
    int i1 = faces[3 * f + 1];
    int i2 = faces[3 * f + 2];
    float ax = vertices[3 * i0 + 0], ay = vertices[3 * i0 + 1], az = vertices[3 * i0 + 2];
    float bx = vertices[3 * i1 + 0], by = vertices[3 * i1 + 1], bz = vertices[3 * i1 + 2];
    float cx = vertices[3 * i2 + 0], cy = vertices[3 * i2 + 1], cz = vertices[3 * i2 + 2];
    float abx = bx - ax, aby = by - ay, abz = bz - az;
    float acx = cx - ax, acy = cy - ay, acz = cz - az;
    float daab = (ax * abx + ay * aby) + az * abz;
    float daac = (ax * acx + ay * acy) + az * acz;
    float dbab = (bx * abx + by * aby) + bz * abz;
    float dbac = (bx * acx + by * acy) + bz * acz;
    float dcab = (cx * abx + cy * aby) + cz * abz;
    float dcac = (cx * acx + cy * acy) + cz * acz;
    fd[0] = ax;  fd[1] = ay;  fd[2] = az;
    fd[3] = bx;  fd[4] = by;  fd[5] = bz;
    fd[6] = cx;  fd[7] = cy;  fd[8] = cz;
    fd[9] = abx; fd[10] = aby; fd[11] = abz;
    fd[12] = acx; fd[13] = acy; fd[14] = acz;
    fd[15] = daab; fd[16] = daac; fd[17] = dbab;
    fd[18] = dbac; fd[19] = dcab; fd[20] = dcac;
}

// Region classification + the (at most 2) divisions the winning region needs.
// Bit-exact vs the reference where-chain (proven in R4).
__device__ __forceinline__ void region_w(
    float d1, float d2, float d3, float d4, float d5, float d6,
    float va, float vb, float vc, float e63, float e65, float denom,
    float& w1, float& w2, float& w3)
{
#pragma clang fp contract(off)
    bool m1 = (d1 <= 0.0f) & (d2 <= 0.0f);
    bool m2 = (d3 >= 0.0f) & (d4 <= d3);
    bool m3 = (vc <= 0.0f) & (d1 >= 0.0f) & (d3 <= 0.0f);
    bool m4 = (d6 >= 0.0f) & (d5 <= d6);
    bool m5 = (vb <= 0.0f) & (d2 >= 0.0f) & (d6 <= 0.0f);
    bool m6 = (va <= 0.0f) & (e63 >= 0.0f) & (e65 >= 0.0f);
    bool anym = m1 | m2 | m3 | m4 | m5 | m6;

    float n1  = m1 ? 0.0f : m2 ? 0.0f : m3 ? d1          : m4 ? 0.0f : m5 ? d2          : m6 ? e63         : vb;
    float ds1 = m1 ? 1.0f : m2 ? 1.0f : m3 ? (d1 - d3)   : m4 ? 1.0f : m5 ? (d2 - d6)   : m6 ? (e63 + e65) : denom;
    ds1 = (ds1 == 0.0f) ? 1.0f : ds1;
    float n2  = anym ? 0.0f : vc;
    float ds2 = anym ? 1.0f : ((denom == 0.0f) ? 1.0f : denom);

    float q1 = n1 / ds1;
    float q2 = n2 / ds2;
    float u = (1.0f - q1) - q2;  // == 1-q1 bit-exactly when q2==0

    w1 = m1 ? 1.0f : m2 ? 0.0f : m3 ? u    : m4 ? 0.0f : m5 ? u    : m6 ? 0.0f : u;
    w2 = m1 ? 0.0f : m2 ? 1.0f : m3 ? q1   : m4 ? 0.0f : m5 ? 0.0f : m6 ? u    : q1;
    w3 = m1 ? 0.0f : m2 ? 0.0f : m3 ? 0.0f : m4 ? 1.0f : m5 ? q1   : m6 ? q1   : q2;
}

// Exact (bit-identical to reference) eval — 5 divides. Used only in k_final.
__device__ __forceinline__ void tri_eval_exact(
    float px, float py, float pz,
    const float* fd,
    float& w1o, float& w2o, float& w3o, float& disto)
{
#pragma clang fp contract(off)
    const float ax = fd[0], ay = fd[1], az = fd[2];
    const float bx = fd[3], by = fd[4], bz = fd[5];
    const float cx = fd[6], cy = fd[7], cz = fd[8];
    const float abx = fd[9], aby = fd[10], abz = fd[11];
    const float acx = fd[12], acy = fd[13], acz = fd[14];
    const float daab = fd[15], daac = fd[16], dbab = fd[17];
    const float dbac = fd[18], dcab = fd[19], dcac = fd[20];

    float pab = fmaf(pz, abz, fmaf(py, aby, px * abx));
    float pac = fmaf(pz, acz, fmaf(py, acy, px * acx));

    float d1 = pab - daab;
    float d2 = pac - daac;
    float d3 = pab - dbab;
    float d4 = pac - dbac;
    float d5 = pab - dcab;
    float d6 = pac - dcac;

    float vc = d1 * d4 - d3 * d2;
    float vb = d5 * d2 - d1 * d6;
    float va = d3 * d6 - d5 * d4;

    float denom = (va + vb) + vc;
    float dn = (denom == 0.0f) ? 1.0f : denom;
    float v7 = vb / dn;
    float w7 = vc / dn;
    float w1 = (1.0f - v7) - w7;
    float w2 = v7;
    float w3 = w7;

    float e63 = d4 - d3;
    float e65 = d5 - d6;
    float t6d = e63 + e65; t6d = (t6d == 0.0f) ? 1.0f : t6d;
    float t6 = e63 / t6d;
    if ((va <= 0.0f) & (e63 >= 0.0f) & (e65 >= 0.0f)) { w1 = 0.0f; w2 = 1.0f - t6; w3 = t6; }

    float t5d = d2 - d6; t5d = (t5d == 0.0f) ? 1.0f : t5d;
    float t5 = d2 / t5d;
    if ((vb <= 0.0f) & (d2 >= 0.0f) & (d6 <= 0.0f)) { w1 = 1.0f - t5; w2 = 0.0f; w3 = t5; }

    if ((d6 >= 0.0f) & (d5 <= d6)) { w1 = 0.0f; w2 = 0.0f; w3 = 1.0f; }

    float t3d = d1 - d3; t3d = (t3d == 0.0f) ? 1.0f : t3d;
    float t3 = d1 / t3d;
    if ((vc <= 0.0f) & (d1 >= 0.0f) & (d3 <= 0.0f)) { w1 = 1.0f - t3; w2 = t3; w3 = 0.0f; }

    if ((d3 >= 0.0f) & (d4 <= d3)) { w1 = 0.0f; w2 = 1.0f; w3 = 0.0f; }

    if ((d1 <= 0.0f) & (d2 <= 0.0f)) { w1 = 1.0f; w2 = 0.0f; w3 = 0.0f; }

    float cpx = (w1 * ax + w2 * bx) + w3 * cx;
    float cpy = (w1 * ay + w2 * by) + w3 * cy;
    float cpz = (w1 * az + w2 * bz) + w3 * cz;
    float dx = px - cpx, dy = py - cpy, dz = pz - cpz;
    float dist = (dx * dx + dy * dy) + dz * dz;

    w1o = w1; w2o = w2; w3o = w3; disto = dist;
}

__global__ __launch_bounds__(TPB) void k_scan(
    const float* __restrict__ points,
    const float* __restrict__ vertices,
    const int* __restrict__ faces,
    unsigned long long* __restrict__ best)
{
#pragma clang fp contract(off)
    // SoA: sq[q][face] so a face-pair's quantity q is one aligned 8B LDS word.
    __shared__ float sq[21][FACES_PER_TILE];

    const int pblk = blockIdx.x;  // 0..P_N/TPB-1
    const int fblk = blockIdx.y;  // 0..F_N/FACES_PER_TILE-1
    const int t = threadIdx.x;

    if (t < FACES_PER_TILE) {
        int f = fblk * FACES_PER_TILE + t;
        float fd[21];
        face_setup(vertices, faces, f, fd);
#pragma unroll
        for (int k = 0; k < 21; ++k) sq[k][t] = fd[k];
    }
    __syncthreads();

    const int p = pblk * TPB + t;
    const float px = points[3 * p + 0];
    const float py = points[3 * p + 1];
    const float pz = points[3 * p + 2];
    const v2f pxv = {px, px};
    const v2f pyv = {py, py};
    const v2f pzv = {pz, pz};

    unsigned int bestdb = 0xffffffffu;
    int bestf = 0;
    const int fbase = fblk * FACES_PER_TILE;

#pragma unroll 2
    for (int j = 0; j < FACES_PER_TILE; j += 2) {
#define LD2(q) (*(const v2f*)&sq[q][j])
        v2f axv = LD2(0),  ayv = LD2(1),  azv = LD2(2);
        v2f bxv = LD2(3),  byv = LD2(4),  bzv = LD2(5);
        v2f cxv = LD2(6),  cyv = LD2(7),  czv = LD2(8);
        v2f abxv = LD2(9),  abyv = LD2(10), abzv = LD2(11);
        v2f acxv = LD2(12), acyv = LD2(13), aczv = LD2(14);
        v2f daabv = LD2(15), daacv = LD2(16), dbabv = LD2(17);
        v2f dbacv = LD2(18), dcabv = LD2(19), dcacv = LD2(20);
#undef LD2

        v2f pab = __builtin_elementwise_fma(pzv, abzv,
                    __builtin_elementwise_fma(pyv, abyv, pxv * abxv));
        v2f pac = __builtin_elementwise_fma(pzv, aczv,
                    __builtin_elementwise_fma(pyv, acyv, pxv * acxv));

        v2f d1 = pab - daabv;
        v2f d2 = pac - daacv;
        v2f d3 = pab - dbabv;
        v2f d4 = pac - dbacv;
        v2f d5 = pab - dcabv;
        v2f d6 = pac - dcacv;

        v2f vcv = d1 * d4 - d3 * d2;
        v2f vbv = d5 * d2 - d1 * d6;
        v2f vav = d3 * d6 - d5 * d4;

        v2f e63 = d4 - d3;
        v2f e65 = d5 - d6;
        v2f denom = (vav + vbv) + vcv;

        float w1a, w2a, w3a, w1b, w2b, w3b;
        region_w(d1.x, d2.x, d3.x, d4.x, d5.x, d6.x,
                 vav.x, vbv.x, vcv.x, e63.x, e65.x, denom.x, w1a, w2a, w3a);
        region_w(d1.y, d2.y, d3.y, d4.y, d5.y, d6.y,
                 vav.y, vbv.y, vcv.y, e63.y, e65.y, denom.y, w1b, w2b, w3b);

        v2f w1v = {w1a, w1b};
        v2f w2v = {w2a, w2b};
        v2f w3v = {w3a, w3b};

        v2f cpx = (w1v * axv + w2v * bxv) + w3v * cxv;
        v2f cpy = (w1v * ayv + w2v * byv) + w3v * cyv;
        v2f cpz = (w1v * azv + w2v * bzv) + w3v * czv;
        v2f dx = pxv - cpx, dy = pyv - cpy, dz = pzv - cpz;
        v2f dist = (dx * dx + dy * dy) + dz * dz;

        float da = dist.x;
        float db = dist.y;
        unsigned int ua = __float_as_uint(da);
        unsigned int ub = __float_as_uint(db);
        if (da != da) ua = 0u;  // NaN acts as -inf (numpy argmin: first NaN wins)
        if (db != db) ub = 0u;
        if (ua < bestdb) { bestdb = ua; bestf = fbase + j; }
        if (ub < bestdb) { bestdb = ub; bestf = fbase + j + 1; }
    }

    unsigned long long key =
        ((unsigned long long)bestdb << 32) | (unsigned int)bestf;
    atomicMin(&best[p], key);
}

__global__ __launch_bounds__(TPB) void k_final(
    const float* __restrict__ points,
    const float* __restrict__ vertices,
    const int* __restrict__ faces,
    const unsigned long long* __restrict__ best,
    float* __restrict__ out)
{
    const int p = blockIdx.x * TPB + threadIdx.x;
    if (p >= P_N) return;
    unsigned long long bk = best[p];
    int f = (int)(bk & 0xffffffffull);

    float fd[21];
    face_setup(vertices, faces, f, fd);

    const float px = points[3 * p + 0];
    const float py = points[3 * p + 1];
    const float pz = points[3 * p + 2];
    float w1, w2, w3, dist;
    tri_eval_exact(px, py, pz, fd, w1, w2, w3, dist);

    out[p] = (float)f;
    out[P_N + p] = w1;
    out[2 * P_N + p] = w2;
    out[3 * P_N + p] = w3;
}

extern "C" void kernel_launch(void* const* d_in, const int* in_sizes, int n_in,
                              void* d_out, int out_size, void* d_ws, size_t ws_size,
                              hipStream_t stream)
{
    const float* points = (const float*)d_in[0];
    const float* vertices = (const float*)d_in[1];
    const int* faces = (const int*)d_in[2];
    float* out = (float*)d_out;
    unsigned long long* best = (unsigned long long*)d_ws;

    hipMemsetAsync(d_ws, 0xFF, P_N * sizeof(unsigned long long), stream);

    dim3 grid(P_N / TPB, F_N / FACES_PER_TILE);
    k_scan<<<grid, TPB, 0, stream>>>(points, vertices, faces, best);
    k_final<<<(P_N + TPB - 1) / TPB, TPB, 0, stream>>>(points, vertices, faces, best, out);
}